// Round 7
// baseline (4817.445 us; speedup 1.0000x reference)
//
#include <hip/hip_runtime.h>
#include <cstdint>
#include <cstddef>

#define BB 2
#define NN 16384
#define SS 4096
#define KK 32
#define FIN 16
#define R2C 0.01f
#define NCHUNK 256   // chunks = 64-slot ranges of the Morton-cell-sorted point array

typedef unsigned long long u64;

// ---------------- fused 32-bit DPP chains (1 instr/step after GCNDPPCombine) ----
// update_dpp(old=own, src=own): shifted-in lanes keep own value -> idempotent.
template <int CTRL>
__device__ __forceinline__ float fstep(float k) {
  const int n = __builtin_amdgcn_update_dpp(__float_as_int(k), __float_as_int(k),
                                            CTRL, 0xf, 0xf, false);
  return fmaxf(k, __int_as_float(n));  // -> v_max_f32_dpp
}
__device__ __forceinline__ float fchain(float k) {
  k = fstep<0x111>(k);  // row_shr:1
  k = fstep<0x112>(k);  // row_shr:2
  k = fstep<0x114>(k);  // row_shr:4
  k = fstep<0x118>(k);  // row_shr:8
  k = fstep<0x142>(k);  // row_bcast15
  k = fstep<0x143>(k);  // row_bcast31
  return k;             // lane 63 holds the wave max
}
template <int CTRL>
__device__ __forceinline__ unsigned int ustep(unsigned int k) {
  const unsigned int n = (unsigned int)__builtin_amdgcn_update_dpp(
      (int)k, (int)k, CTRL, 0xf, 0xf, false);
  return k > n ? k : n;  // -> v_max_u32_dpp
}
__device__ __forceinline__ unsigned int uchain(unsigned int k) {
  k = ustep<0x111>(k);
  k = ustep<0x112>(k);
  k = ustep<0x114>(k);
  k = ustep<0x118>(k);
  k = ustep<0x142>(k);
  k = ustep<0x143>(k);
  return k;             // lane 63 holds the wave max
}

// ---------------- f64-packed-key DPP wave max (phase C only, proven r0) --------
// keys are (f32bits(dmin)<<32)|rank: high bit 0 -> positive finite double, so
// f64 ordering == u64 ordering; one v_max_f64 replaces cmp+cndmask per step.
template <int CTRL>
__device__ __forceinline__ double kstep64(double k) {
  const u64 kb = (u64)__double_as_longlong(k);
  const int lo = (int)(unsigned int)kb;
  const int hi = (int)(unsigned int)(kb >> 32);
  const int nlo = __builtin_amdgcn_update_dpp(lo, lo, CTRL, 0xf, 0xf, false);
  const int nhi = __builtin_amdgcn_update_dpp(hi, hi, CTRL, 0xf, 0xf, false);
  const double nk = __longlong_as_double(
      (long long)(((u64)(unsigned int)nhi << 32) | (unsigned int)nlo));
  return fmax(k, nk);
}
__device__ __forceinline__ double kchain64(double k) {
  k = kstep64<0x111>(k);
  k = kstep64<0x112>(k);
  k = kstep64<0x114>(k);
  k = kstep64<0x118>(k);
  k = kstep64<0x142>(k);
  k = kstep64<0x143>(k);
  return k;  // lane 63 holds the wave max
}

// ---------------- binning: counting-sort points into Morton-ordered cells ----------------
__device__ __forceinline__ int part3(int x) {  // 3 bits -> bits 0,3,6
  return (x & 1) | ((x & 2) << 2) | ((x & 4) << 4);
}

__global__ __launch_bounds__(512) void bin_kernel(const float* __restrict__ pos,
                                                  float4* __restrict__ cellpts,
                                                  float4* __restrict__ bboxLo,
                                                  float4* __restrict__ bboxHi) {
  const int b = blockIdx.x, t = threadIdx.x;
  const float* __restrict__ p = pos + (size_t)b * NN * 3;
  __shared__ int hist[512], sA[512], sB[512];
  hist[t] = 0;
  __syncthreads();
  int cidc[NN / 512];  // 32 per thread
#pragma unroll
  for (int m = 0; m < NN / 512; ++m) {
    const int i = m * 512 + t;
    const float x = p[i * 3 + 0], y = p[i * 3 + 1], z = p[i * 3 + 2];
    const int cx = min(7, (int)(x * 8.0f));
    const int cy = min(7, (int)(y * 8.0f));
    const int cz = min(7, (int)(z * 8.0f));
    const int cid = part3(cx) | (part3(cy) << 1) | (part3(cz) << 2);  // Morton
    cidc[m] = cid;
    atomicAdd(&hist[cid], 1);
  }
  __syncthreads();
  sA[t] = hist[t];
  __syncthreads();
  int* src = sA;
  int* dst = sB;
  for (int off = 1; off < 512; off <<= 1) {
    int v = src[t];
    if (t >= off) v += src[t - off];
    dst[t] = v;
    __syncthreads();
    int* tmp = src; src = dst; dst = tmp;
  }
  const int excl = (t == 0) ? 0 : src[t - 1];
  __syncthreads();
  hist[t] = excl;
  __syncthreads();
#pragma unroll
  for (int m = 0; m < NN / 512; ++m) {
    const int i = m * 512 + t;
    const int slot = atomicAdd(&hist[cidc[m]], 1);
    cellpts[(size_t)b * NN + slot] =
        make_float4(p[i * 3 + 0], p[i * 3 + 1], p[i * 3 + 2], __int_as_float(i));
  }
  __threadfence_block();
  __syncthreads();
  if (t < NCHUNK) {
    float4 lo = make_float4(1e30f, 1e30f, 1e30f, 0.0f);
    float4 hi = make_float4(-1e30f, -1e30f, -1e30f, 0.0f);
    for (int k = 0; k < 64; ++k) {
      const float4 q = cellpts[(size_t)b * NN + t * 64 + k];
      lo.x = fminf(lo.x, q.x); lo.y = fminf(lo.y, q.y); lo.z = fminf(lo.z, q.z);
      hi.x = fmaxf(hi.x, q.x); hi.y = fmaxf(hi.y, q.y); hi.z = fmaxf(hi.z, q.z);
    }
    bboxLo[b * NCHUNK + t] = lo;
    bboxHi[b * NCHUNK + t] = hi;
  }
}

// ---------------- FPS: one 512-thread block (8 waves) per batch ----------------
// Exact AABB-pruned FPS, r0 sync structure (ONE barrier/iter, double-buffered
// u64 keys). r7: 8 waves x 32 owned chunks (was 16 x 16). Phase B's total work
// is block-wide fixed, but phases A + C + loop overhead replicate PER WAVE:
// halving the wave count halves that replication (~180 issue-cy/SIMD/iter) and
// halves C's lockstep wall time. Arrays grow to 32 entries (~190 VGPR -> 2
// waves/SIMD, pinned by __launch_bounds__(512,2)); chunk c owned by wave
// (c & 7), register index cc = c >> 3. All proven r6 pieces unchanged: dmin
// register-resident, readlane + v_writelane key gather, ONE ds_write_b64 per
// wave, tie fast path, register-carried kOwn, phase C over 256 keys with
// rank-slot coords fetch.
// Key format (dminbits<<32)|((16383-pid)<<14|chunk<<6|lane): exact
// (dmin desc, pid asc) order; decode fi = 16383-(lo>>14); low 14 bits of
// rank == absolute sorted slot (ownership-mapping independent).
#define FPS_T 512
#define FPS_NW 8

__global__ __launch_bounds__(FPS_T, 2) void fps_kernel(const float* __restrict__ pos,
                                                       const float4* __restrict__ cellpts,
                                                       const float4* __restrict__ bboxLo,
                                                       const float4* __restrict__ bboxHi,
                                                       int* __restrict__ idx_out) {
  const int b = blockIdx.x;
  const int t = threadIdx.x;
  const int wid = t >> 6;   // 0..7
  const int lane = t & 63;
  const float* __restrict__ p = pos + (size_t)b * NN * 3;
  const float4* __restrict__ cp = cellpts + (size_t)b * NN;

  __shared__ __align__(16) u64 sKey[2][NCHUNK];  // double-buffered chunk keys (4 KB)

  const int cown = ((lane & 31) << 3) | wid;  // owned chunk (real for lane<32)
  const int slotOwn = (wid << 5) | (lane & 31);
  const float4 blo = bboxLo[b * NCHUNK + cown];
  const float4 bhi = bboxHi[b * NCHUNK + cown];

  // this wave's 32 owned chunks: coords + encoded rank + dmin, ALL in registers.
  // rank = (16383-pid)<<14 | chunk<<6 | lane : low 14 bits == sorted slot.
  float px[32], py[32], pz[32], dmn[32];
  unsigned int rp[32];
#pragma unroll
  for (int cc = 0; cc < 32; ++cc) {
    const int c = (cc << 3) | wid;
    const float4 q = cp[(size_t)((c << 6) + lane)];
    px[cc] = q.x; py[cc] = q.y; pz[cc] = q.z;
    const unsigned int pid = (unsigned int)__float_as_int(q.w);
    rp[cc] = ((16383u - pid) << 14) | ((unsigned int)c << 6) | (unsigned int)lane;
    dmn[cc] = 1e10f;
  }

  const u64 initKey = ((u64)(unsigned int)__float_as_int(1e30f) << 32);
  if (t < NCHUNK) sKey[0][t] = initKey;
  if (t == 0) idx_out[b * SS + 0] = 0;
  float lx = p[0], ly = p[1], lz = p[2];
  int kHi = __float_as_int(1e30f);  // owned-slot key, carried across iterations
  int kLo = 0;
  __syncthreads();

  int buf = 0;

  for (int it = 1; it < SS; ++it) {
    // ---- A: test owned chunks (pure VALU, boxes + key in regs) ----
    const float mvOwn = __int_as_float(kHi);
    const float ax = fmaxf(fmaxf(blo.x - lx, lx - bhi.x), 0.0f);
    const float ay = fmaxf(fmaxf(blo.y - ly, ly - bhi.y), 0.0f);
    const float az = fmaxf(fmaxf(blo.z - lz, lz - bhi.z), 0.0f);
    const float bl2 = ax * ax + ay * ay + az * az;
    // skip iff conservative lower bound exceeds chunk max dmin: then
    // min(dmin_j, d_j) == dmin_j exactly for every member (bit-exact skip).
    const bool act = (lane < 32) && !(bl2 * 0.99999f > mvOwn);
    const unsigned int mm = (unsigned int)__ballot(act);  // uniform, low 32 bits

    // carry defaults: inactive owned chunks keep their old key
    int vhi = kHi;
    int vlo = kLo;

    // ---- B: predicated unroll over the 32 owned chunks, zero LDS traffic ----
    // (macro-stamped so the writelane lane index is a literal immediate)
#define BODY(cc)                                                                 \
    if (mm & (1u << cc)) {                                                       \
      const float dx = px[cc] - lx, dy = py[cc] - ly, dz = pz[cc] - lz;          \
      const float d = __fadd_rn(__fadd_rn(__fmul_rn(dx, dx), __fmul_rn(dy, dy)), \
                                __fmul_rn(dz, dz));                              \
      const float nd = fminf(dmn[cc], d);                                        \
      dmn[cc] = nd;                                                              \
      const float cm = fchain(nd); /* lane 63: chunk max */                      \
      const int cmb = __builtin_amdgcn_readlane(__float_as_int(cm), 63);         \
      const u64 tmask = __ballot(nd == __int_as_float(cmb));                     \
      int tts;                                                                   \
      if (__builtin_expect((tmask & (tmask - 1)) != 0, 0)) { /* true tie */      \
        unsigned int tt = (nd == __int_as_float(cmb)) ? rp[cc] : 0u;             \
        tt = uchain(tt); /* lane 63: max rank == lowest pid among tied */        \
        tts = __builtin_amdgcn_readlane((int)tt, 63);                            \
      } else { /* unique argmax lane: one variable-lane readlane */              \
        tts = __builtin_amdgcn_readlane((int)rp[cc],                             \
                                        (int)__builtin_ctzll(tmask));            \
      }                                                                          \
      asm("v_writelane_b32 %0, %1, " #cc : "+v"(vhi) : "s"(cmb));                \
      asm("v_writelane_b32 %0, %1, " #cc : "+v"(vlo) : "s"(tts));                \
    }
    BODY(0) BODY(1) BODY(2) BODY(3) BODY(4) BODY(5) BODY(6) BODY(7)
    BODY(8) BODY(9) BODY(10) BODY(11) BODY(12) BODY(13) BODY(14) BODY(15)
    BODY(16) BODY(17) BODY(18) BODY(19) BODY(20) BODY(21) BODY(22) BODY(23)
    BODY(24) BODY(25) BODY(26) BODY(27) BODY(28) BODY(29) BODY(30) BODY(31)
#undef BODY

    // ONE ds_write_b64 covering all 32 owned slots (new keys + carries)
    if (lane < 32)
      sKey[buf ^ 1][slotOwn] = ((u64)(unsigned int)vhi << 32) | (unsigned int)vlo;
    kHi = vhi;  // register carry of the owned-slot key (valid where used)
    kLo = vlo;
    __syncthreads();  // the ONLY barrier per iteration
    buf ^= 1;

    // ---- C: global winner over 256 packed chunk keys (all waves, redundant) ----
    const ulonglong2 ka = *(const ulonglong2*)&sKey[buf][2 * lane];
    const ulonglong2 kb = *(const ulonglong2*)&sKey[buf][128 + 2 * lane];
    double bk = fmax(fmax(__longlong_as_double((long long)ka.x),
                          __longlong_as_double((long long)ka.y)),
                     fmax(__longlong_as_double((long long)kb.x),
                          __longlong_as_double((long long)kb.y)));
    bk = kchain64(bk);
    const unsigned int lo63 = (unsigned int)__builtin_amdgcn_readlane(
        (int)(unsigned int)(u64)__double_as_longlong(bk), 63);
    const int fi = 16383 - (int)(lo63 >> 14);  // decode winning original index
    if (t == 0) idx_out[b * SS + it] = fi;
    // winner coords via sorted slot (low 14 bits of rank): ONE uniform 16B load
    const int slot = (int)(lo63 & 0x3FFFu);
    const float4 wq = cp[(size_t)slot];
    lx = wq.x;
    ly = wq.y;
    lz = wq.z;
  }
}

// ---------------- Ball query: one wave per centroid ----------------
__global__ __launch_bounds__(256) void ballq_kernel(const float* __restrict__ pos,
                                                    const int* __restrict__ idx,
                                                    int* __restrict__ nbr,
                                                    int* __restrict__ cnt,
                                                    float* __restrict__ outC,
                                                    float* __restrict__ outB) {
  const int cs = blockIdx.x * 4 + (threadIdx.x >> 6);
  const int lane = threadIdx.x & 63;
  const int b = cs >> 12;           // S = 4096
  const int s = cs & (SS - 1);
  const float* __restrict__ p = pos + (size_t)b * NN * 3;
  const int ci = idx[cs];
  const float cx = p[ci * 3 + 0], cy = p[ci * 3 + 1], cz = p[ci * 3 + 2];
  // remove_self_loops: global src b*N+i == global dst b*S+s -> only b==0, i==s
  const int excl = (b == 0) ? s : -1;
  int count = 0;
  for (int tile = 0; tile < NN / 64; ++tile) {
    const int i = tile * 64 + lane;
    const float dx = cx - p[i * 3 + 0];
    const float dy = cy - p[i * 3 + 1];
    const float dz = cz - p[i * 3 + 2];
    const float d2 = __fadd_rn(__fadd_rn(__fmul_rn(dx, dx), __fmul_rn(dy, dy)), __fmul_rn(dz, dz));
    const bool in = (d2 <= R2C) && (i != excl);
    const unsigned long long m = __ballot(in);
    if (in) {
      const int rank = count + (int)__popcll(m & ((1ull << lane) - 1ull));
      if (rank < KK) nbr[cs * KK + rank] = i;
    }
    count += (int)__popcll(m);
    if (count >= KK) break;
  }
  if (lane == 0) {
    cnt[cs] = count < KK ? count : KK;
    outC[cs * 3 + 0] = cx;
    outC[cs * 3 + 1] = cy;
    outC[cs * 3 + 2] = cz;
    outB[cs] = (float)b;
  }
}

// ---------------- MLP + max: one block (128 thr) per centroid ----------------
#define EE 33
__global__ __launch_bounds__(128) void mlp_kernel(const float* __restrict__ x,
                                                  const float* __restrict__ pos,
                                                  const int* __restrict__ nbr,
                                                  const int* __restrict__ cnt,
                                                  const float* __restrict__ W1,
                                                  const float* __restrict__ b1,
                                                  const float* __restrict__ W2,
                                                  const float* __restrict__ b2,
                                                  const float* __restrict__ W3,
                                                  const float* __restrict__ b3,
                                                  const float* __restrict__ outC,
                                                  float* __restrict__ outX) {
  __shared__ float sF[EE][20];
  __shared__ float sH1[EE][64];
  __shared__ float sH2[EE][64];
  __shared__ int sValid[EE];

  const int cs = blockIdx.x;
  const int tid = threadIdx.x;
  const int b = cs >> 12;
  const int c = tid & 63;
  const int half = tid >> 6;

  float w1c[19], w2c[64], w3c[64];
#pragma unroll
  for (int k = 0; k < 19; ++k) w1c[k] = W1[k * 64 + c];
#pragma unroll
  for (int k = 0; k < 64; ++k) w2c[k] = W2[k * 64 + c];
#pragma unroll
  for (int k = 0; k < 64; ++k) w3c[k] = W3[k * 128 + tid];
  const float b1c = b1[c], b2c = b2[c], b3c = b3[tid];

  if (tid < EE) {
    const float ccx = outC[cs * 3 + 0], ccy = outC[cs * 3 + 1], ccz = outC[cs * 3 + 2];
    int row;
    bool valid;
    if (tid < KK) {
      const int cn = cnt[cs];
      valid = tid < cn;
      const int j = valid ? nbr[cs * KK + tid] : 0;
      row = b * NN + j;
    } else {
      // PyG add_self_loops quirk: src is flat point index dflat = b*S+s = cs
      valid = true;
      row = cs;
    }
    for (int f = 0; f < FIN; ++f) sF[tid][f] = x[(size_t)row * FIN + f];
    sF[tid][16] = pos[(size_t)row * 3 + 0] - ccx;
    sF[tid][17] = pos[(size_t)row * 3 + 1] - ccy;
    sF[tid][18] = pos[(size_t)row * 3 + 2] - ccz;
    sValid[tid] = valid ? 1 : 0;
  }
  __syncthreads();
  for (int e = half; e < EE; e += 2) {
    float acc = b1c;
#pragma unroll
    for (int k = 0; k < 19; ++k) acc += sF[e][k] * w1c[k];
    sH1[e][c] = fmaxf(acc, 0.0f);
  }
  __syncthreads();
  for (int e = half; e < EE; e += 2) {
    float acc = b2c;
#pragma unroll
    for (int k = 0; k < 64; ++k) acc += sH1[e][k] * w2c[k];
    sH2[e][c] = fmaxf(acc, 0.0f);
  }
  __syncthreads();
  float mx = -1e30f;
  for (int e = 0; e < EE; ++e) {
    if (sValid[e]) {
      float acc = b3c;
#pragma unroll
      for (int k = 0; k < 64; ++k) acc += sH2[e][k] * w3c[k];
      mx = fmaxf(mx, acc);
    }
  }
  outX[(size_t)cs * 128 + tid] = mx;
}

extern "C" void kernel_launch(void* const* d_in, const int* in_sizes, int n_in,
                              void* d_out, int out_size, void* d_ws, size_t ws_size,
                              hipStream_t stream) {
  const float* x = (const float*)d_in[0];
  const float* pos = (const float*)d_in[1];
  const float* W1 = (const float*)d_in[3];
  const float* b1 = (const float*)d_in[4];
  const float* W2 = (const float*)d_in[5];
  const float* b2 = (const float*)d_in[6];
  const float* W3 = (const float*)d_in[7];
  const float* b3 = (const float*)d_in[8];

  float* out = (float*)d_out;
  float* outX = out;                               // [B*S,128]
  float* outC = out + (size_t)BB * SS * 128;       // [B*S,3]
  float* outB = outC + (size_t)BB * SS * 3;        // [B*S]

  float4* cellpts = (float4*)d_ws;                         // BB*NN float4
  float4* bboxLo = cellpts + (size_t)BB * NN;              // BB*256
  float4* bboxHi = bboxLo + BB * NCHUNK;                   // BB*256
  int* idx = (int*)(bboxHi + BB * NCHUNK);                 // BB*SS
  int* nbr = idx + BB * SS;                                // BB*SS*KK
  int* cnt = nbr + (size_t)BB * SS * KK;                   // BB*SS

  hipLaunchKernelGGL(bin_kernel, dim3(BB), dim3(512), 0, stream, pos, cellpts, bboxLo, bboxHi);
  hipLaunchKernelGGL(fps_kernel, dim3(BB), dim3(FPS_T), 0, stream, pos, cellpts, bboxLo, bboxHi, idx);
  hipLaunchKernelGGL(ballq_kernel, dim3(BB * SS / 4), dim3(256), 0, stream,
                     pos, idx, nbr, cnt, outC, outB);
  hipLaunchKernelGGL(mlp_kernel, dim3(BB * SS), dim3(128), 0, stream,
                     x, pos, nbr, cnt, W1, b1, W2, b2, W3, b3, outC, outX);
}

// Round 8
// 3973.856 us; speedup vs baseline: 1.2123x; 1.2123x over previous
//
#include <hip/hip_runtime.h>
#include <cstdint>
#include <cstddef>

#define BB 2
#define NN 16384
#define SS 4096
#define KK 32
#define FIN 16
#define R2C 0.01f
#define NCHUNK 256   // chunks = 64-slot ranges of the Morton-cell-sorted point array

typedef unsigned long long u64;

// ---------------- fused 32-bit DPP chains (1 instr/step after GCNDPPCombine) ----
// update_dpp(old=own, src=own): shifted-in lanes keep own value -> idempotent.
template <int CTRL>
__device__ __forceinline__ float fstep(float k) {
  const int n = __builtin_amdgcn_update_dpp(__float_as_int(k), __float_as_int(k),
                                            CTRL, 0xf, 0xf, false);
  return fmaxf(k, __int_as_float(n));  // -> v_max_f32_dpp
}
__device__ __forceinline__ float fchain(float k) {
  k = fstep<0x111>(k);  // row_shr:1
  k = fstep<0x112>(k);  // row_shr:2
  k = fstep<0x114>(k);  // row_shr:4
  k = fstep<0x118>(k);  // row_shr:8
  k = fstep<0x142>(k);  // row_bcast15
  k = fstep<0x143>(k);  // row_bcast31
  return k;             // lane 63 holds the wave max
}
template <int CTRL>
__device__ __forceinline__ unsigned int ustep(unsigned int k) {
  const unsigned int n = (unsigned int)__builtin_amdgcn_update_dpp(
      (int)k, (int)k, CTRL, 0xf, 0xf, false);
  return k > n ? k : n;  // -> v_max_u32_dpp
}
__device__ __forceinline__ unsigned int uchain(unsigned int k) {
  k = ustep<0x111>(k);
  k = ustep<0x112>(k);
  k = ustep<0x114>(k);
  k = ustep<0x118>(k);
  k = ustep<0x142>(k);
  k = ustep<0x143>(k);
  return k;             // lane 63 holds the wave max
}

// ---------------- f64-packed-key DPP wave max (phase C only, proven r0) --------
// keys are (f32bits(dmin)<<32)|rank: high bit 0 -> positive finite double, so
// f64 ordering == u64 ordering; one v_max_f64 replaces cmp+cndmask per step.
template <int CTRL>
__device__ __forceinline__ double kstep64(double k) {
  const u64 kb = (u64)__double_as_longlong(k);
  const int lo = (int)(unsigned int)kb;
  const int hi = (int)(unsigned int)(kb >> 32);
  const int nlo = __builtin_amdgcn_update_dpp(lo, lo, CTRL, 0xf, 0xf, false);
  const int nhi = __builtin_amdgcn_update_dpp(hi, hi, CTRL, 0xf, 0xf, false);
  const double nk = __longlong_as_double(
      (long long)(((u64)(unsigned int)nhi << 32) | (unsigned int)nlo));
  return fmax(k, nk);
}
__device__ __forceinline__ double kchain64(double k) {
  k = kstep64<0x111>(k);
  k = kstep64<0x112>(k);
  k = kstep64<0x114>(k);
  k = kstep64<0x118>(k);
  k = kstep64<0x142>(k);
  k = kstep64<0x143>(k);
  return k;  // lane 63 holds the wave max
}

// ---------------- binning: counting-sort points into Morton-ordered cells ----------------
__device__ __forceinline__ int part3(int x) {  // 3 bits -> bits 0,3,6
  return (x & 1) | ((x & 2) << 2) | ((x & 4) << 4);
}

__global__ __launch_bounds__(512) void bin_kernel(const float* __restrict__ pos,
                                                  float4* __restrict__ cellpts,
                                                  float4* __restrict__ bboxLo,
                                                  float4* __restrict__ bboxHi) {
  const int b = blockIdx.x, t = threadIdx.x;
  const float* __restrict__ p = pos + (size_t)b * NN * 3;
  __shared__ int hist[512], sA[512], sB[512];
  hist[t] = 0;
  __syncthreads();
  int cidc[NN / 512];  // 32 per thread
#pragma unroll
  for (int m = 0; m < NN / 512; ++m) {
    const int i = m * 512 + t;
    const float x = p[i * 3 + 0], y = p[i * 3 + 1], z = p[i * 3 + 2];
    const int cx = min(7, (int)(x * 8.0f));
    const int cy = min(7, (int)(y * 8.0f));
    const int cz = min(7, (int)(z * 8.0f));
    const int cid = part3(cx) | (part3(cy) << 1) | (part3(cz) << 2);  // Morton
    cidc[m] = cid;
    atomicAdd(&hist[cid], 1);
  }
  __syncthreads();
  sA[t] = hist[t];
  __syncthreads();
  int* src = sA;
  int* dst = sB;
  for (int off = 1; off < 512; off <<= 1) {
    int v = src[t];
    if (t >= off) v += src[t - off];
    dst[t] = v;
    __syncthreads();
    int* tmp = src; src = dst; dst = tmp;
  }
  const int excl = (t == 0) ? 0 : src[t - 1];
  __syncthreads();
  hist[t] = excl;
  __syncthreads();
#pragma unroll
  for (int m = 0; m < NN / 512; ++m) {
    const int i = m * 512 + t;
    const int slot = atomicAdd(&hist[cidc[m]], 1);
    cellpts[(size_t)b * NN + slot] =
        make_float4(p[i * 3 + 0], p[i * 3 + 1], p[i * 3 + 2], __int_as_float(i));
  }
  __threadfence_block();
  __syncthreads();
  if (t < NCHUNK) {
    float4 lo = make_float4(1e30f, 1e30f, 1e30f, 0.0f);
    float4 hi = make_float4(-1e30f, -1e30f, -1e30f, 0.0f);
    for (int k = 0; k < 64; ++k) {
      const float4 q = cellpts[(size_t)b * NN + t * 64 + k];
      lo.x = fminf(lo.x, q.x); lo.y = fminf(lo.y, q.y); lo.z = fminf(lo.z, q.z);
      hi.x = fmaxf(hi.x, q.x); hi.y = fmaxf(hi.y, q.y); hi.z = fmaxf(hi.z, q.z);
    }
    bboxLo[b * NCHUNK + t] = lo;
    bboxHi[b * NCHUNK + t] = hi;
  }
}

// ---------------- FPS: one 1024-thread block (16 waves) per batch ----------------
// Exact AABB-pruned FPS, r6 structure (proven best: ONE barrier/iter,
// double-buffered u64 keys, 16 waves x 16 register-resident chunks, VGPR ~60).
// r7's 8x32 variant SPILLED (VGPR 108 < 160 needed) and regressed — reverted.
// r8: no-improvement skip — the AABB test is conservative; for admitted chunks
// where no lane's distance actually shrinks (nd == dmn[cc] all lanes, tested
// with one cmp + ballot), the chunk key is bit-exactly unchanged and vhi/vlo
// already carry it, so the fchain + tie-break + writelanes are skipped
// (wave-uniform branch). Break-even skip rate ~12%; expected 30-50%.
// Key format (dminbits<<32)|((16383-pid)<<14|chunk<<6|lane): exact
// (dmin desc, pid asc) order; decode fi = 16383-(lo>>14); low 14 bits of
// rank == absolute sorted slot -> winner coords via one uniform 16B load.
#define FPS_T 1024
#define FPS_NW 16

__global__ __launch_bounds__(FPS_T, 1) void fps_kernel(const float* __restrict__ pos,
                                                       const float4* __restrict__ cellpts,
                                                       const float4* __restrict__ bboxLo,
                                                       const float4* __restrict__ bboxHi,
                                                       int* __restrict__ idx_out) {
  const int b = blockIdx.x;
  const int t = threadIdx.x;
  const int wid = t >> 6;   // 0..15
  const int lane = t & 63;
  const float* __restrict__ p = pos + (size_t)b * NN * 3;
  const float4* __restrict__ cp = cellpts + (size_t)b * NN;

  __shared__ __align__(16) u64 sKey[2][NCHUNK];  // double-buffered chunk keys (4 KB)

  const int cown = ((lane & 15) << 4) | wid;  // owned chunk (real for lane<16)
  const int slotOwn = (wid << 4) | (lane & 15);
  const float4 blo = bboxLo[b * NCHUNK + cown];
  const float4 bhi = bboxHi[b * NCHUNK + cown];

  // this wave's 16 owned chunks: coords + encoded rank + dmin, ALL in registers.
  // rank = (16383-pid)<<14 | chunk<<6 | lane : low 14 bits == sorted slot.
  float px[16], py[16], pz[16], dmn[16];
  unsigned int rp[16];
#pragma unroll
  for (int cc = 0; cc < 16; ++cc) {
    const int c = (cc << 4) | wid;
    const float4 q = cp[(size_t)((c << 6) + lane)];
    px[cc] = q.x; py[cc] = q.y; pz[cc] = q.z;
    const unsigned int pid = (unsigned int)__float_as_int(q.w);
    rp[cc] = ((16383u - pid) << 14) | ((unsigned int)c << 6) | (unsigned int)lane;
    dmn[cc] = 1e10f;
  }

  const u64 initKey = ((u64)(unsigned int)__float_as_int(1e30f) << 32);
  if (t < NCHUNK) sKey[0][t] = initKey;
  if (t == 0) idx_out[b * SS + 0] = 0;
  float lx = p[0], ly = p[1], lz = p[2];
  int kHi = __float_as_int(1e30f);  // owned-slot key, carried across iterations
  int kLo = 0;
  __syncthreads();

  int buf = 0;

  for (int it = 1; it < SS; ++it) {
    // ---- A: test owned chunks (pure VALU, boxes + key in regs) ----
    const float mvOwn = __int_as_float(kHi);
    const float ax = fmaxf(fmaxf(blo.x - lx, lx - bhi.x), 0.0f);
    const float ay = fmaxf(fmaxf(blo.y - ly, ly - bhi.y), 0.0f);
    const float az = fmaxf(fmaxf(blo.z - lz, lz - bhi.z), 0.0f);
    const float bl2 = ax * ax + ay * ay + az * az;
    // skip iff conservative lower bound exceeds chunk max dmin: then
    // min(dmin_j, d_j) == dmin_j exactly for every member (bit-exact skip).
    const bool act = (lane < 16) && !(bl2 * 0.99999f > mvOwn);
    const unsigned int mm = (unsigned int)__ballot(act);  // uniform, low 16 bits

    // carry defaults: inactive owned chunks keep their old key
    int vhi = kHi;
    int vlo = kLo;

    // ---- B: predicated unroll over the 16 owned chunks, zero LDS traffic ----
    // (macro-stamped so the writelane lane index is a literal immediate)
#define BODY(cc)                                                                 \
    if (mm & (1u << cc)) {                                                       \
      const float dx = px[cc] - lx, dy = py[cc] - ly, dz = pz[cc] - lz;          \
      const float d = __fadd_rn(__fadd_rn(__fmul_rn(dx, dx), __fmul_rn(dy, dy)), \
                                __fmul_rn(dz, dz));                              \
      const float nd = fminf(dmn[cc], d);                                        \
      if (__ballot(nd < dmn[cc])) { /* some lane improved: key may change */     \
        dmn[cc] = nd;                                                            \
        const float cm = fchain(nd); /* lane 63: chunk max */                    \
        const int cmb = __builtin_amdgcn_readlane(__float_as_int(cm), 63);       \
        const u64 tmask = __ballot(nd == __int_as_float(cmb));                   \
        int tts;                                                                 \
        if (__builtin_expect((tmask & (tmask - 1)) != 0, 0)) { /* true tie */    \
          unsigned int tt = (nd == __int_as_float(cmb)) ? rp[cc] : 0u;           \
          tt = uchain(tt); /* lane 63: max rank == lowest pid among tied */      \
          tts = __builtin_amdgcn_readlane((int)tt, 63);                          \
        } else { /* unique argmax lane: one variable-lane readlane */            \
          tts = __builtin_amdgcn_readlane((int)rp[cc],                           \
                                          (int)__builtin_ctzll(tmask));          \
        }                                                                        \
        asm("v_writelane_b32 %0, %1, " #cc : "+v"(vhi) : "s"(cmb));              \
        asm("v_writelane_b32 %0, %1, " #cc : "+v"(vlo) : "s"(tts));              \
      } /* else: no lane improved -> key bit-exactly unchanged, carry holds */   \
    }
    BODY(0) BODY(1) BODY(2) BODY(3) BODY(4) BODY(5) BODY(6) BODY(7)
    BODY(8) BODY(9) BODY(10) BODY(11) BODY(12) BODY(13) BODY(14) BODY(15)
#undef BODY

    // ONE ds_write_b64 covering all 16 owned slots (new keys + carries)
    if (lane < 16)
      sKey[buf ^ 1][slotOwn] = ((u64)(unsigned int)vhi << 32) | (unsigned int)vlo;
    kHi = vhi;  // register carry of the owned-slot key (valid where used)
    kLo = vlo;
    __syncthreads();  // the ONLY barrier per iteration
    buf ^= 1;

    // ---- C: global winner over 256 packed chunk keys (all waves, redundant) ----
    const ulonglong2 ka = *(const ulonglong2*)&sKey[buf][2 * lane];
    const ulonglong2 kb = *(const ulonglong2*)&sKey[buf][128 + 2 * lane];
    double bk = fmax(fmax(__longlong_as_double((long long)ka.x),
                          __longlong_as_double((long long)ka.y)),
                     fmax(__longlong_as_double((long long)kb.x),
                          __longlong_as_double((long long)kb.y)));
    bk = kchain64(bk);
    const unsigned int lo63 = (unsigned int)__builtin_amdgcn_readlane(
        (int)(unsigned int)(u64)__double_as_longlong(bk), 63);
    const int fi = 16383 - (int)(lo63 >> 14);  // decode winning original index
    if (t == 0) idx_out[b * SS + it] = fi;
    // winner coords via sorted slot (low 14 bits of rank): ONE uniform 16B load
    const int slot = (int)(lo63 & 0x3FFFu);
    const float4 wq = cp[(size_t)slot];
    lx = wq.x;
    ly = wq.y;
    lz = wq.z;
  }
}

// ---------------- Ball query: one wave per centroid ----------------
__global__ __launch_bounds__(256) void ballq_kernel(const float* __restrict__ pos,
                                                    const int* __restrict__ idx,
                                                    int* __restrict__ nbr,
                                                    int* __restrict__ cnt,
                                                    float* __restrict__ outC,
                                                    float* __restrict__ outB) {
  const int cs = blockIdx.x * 4 + (threadIdx.x >> 6);
  const int lane = threadIdx.x & 63;
  const int b = cs >> 12;           // S = 4096
  const int s = cs & (SS - 1);
  const float* __restrict__ p = pos + (size_t)b * NN * 3;
  const int ci = idx[cs];
  const float cx = p[ci * 3 + 0], cy = p[ci * 3 + 1], cz = p[ci * 3 + 2];
  // remove_self_loops: global src b*N+i == global dst b*S+s -> only b==0, i==s
  const int excl = (b == 0) ? s : -1;
  int count = 0;
  for (int tile = 0; tile < NN / 64; ++tile) {
    const int i = tile * 64 + lane;
    const float dx = cx - p[i * 3 + 0];
    const float dy = cy - p[i * 3 + 1];
    const float dz = cz - p[i * 3 + 2];
    const float d2 = __fadd_rn(__fadd_rn(__fmul_rn(dx, dx), __fmul_rn(dy, dy)), __fmul_rn(dz, dz));
    const bool in = (d2 <= R2C) && (i != excl);
    const unsigned long long m = __ballot(in);
    if (in) {
      const int rank = count + (int)__popcll(m & ((1ull << lane) - 1ull));
      if (rank < KK) nbr[cs * KK + rank] = i;
    }
    count += (int)__popcll(m);
    if (count >= KK) break;
  }
  if (lane == 0) {
    cnt[cs] = count < KK ? count : KK;
    outC[cs * 3 + 0] = cx;
    outC[cs * 3 + 1] = cy;
    outC[cs * 3 + 2] = cz;
    outB[cs] = (float)b;
  }
}

// ---------------- MLP + max: one block (128 thr) per centroid ----------------
#define EE 33
__global__ __launch_bounds__(128) void mlp_kernel(const float* __restrict__ x,
                                                  const float* __restrict__ pos,
                                                  const int* __restrict__ nbr,
                                                  const int* __restrict__ cnt,
                                                  const float* __restrict__ W1,
                                                  const float* __restrict__ b1,
                                                  const float* __restrict__ W2,
                                                  const float* __restrict__ b2,
                                                  const float* __restrict__ W3,
                                                  const float* __restrict__ b3,
                                                  const float* __restrict__ outC,
                                                  float* __restrict__ outX) {
  __shared__ float sF[EE][20];
  __shared__ float sH1[EE][64];
  __shared__ float sH2[EE][64];
  __shared__ int sValid[EE];

  const int cs = blockIdx.x;
  const int tid = threadIdx.x;
  const int b = cs >> 12;
  const int c = tid & 63;
  const int half = tid >> 6;

  float w1c[19], w2c[64], w3c[64];
#pragma unroll
  for (int k = 0; k < 19; ++k) w1c[k] = W1[k * 64 + c];
#pragma unroll
  for (int k = 0; k < 64; ++k) w2c[k] = W2[k * 64 + c];
#pragma unroll
  for (int k = 0; k < 64; ++k) w3c[k] = W3[k * 128 + tid];
  const float b1c = b1[c], b2c = b2[c], b3c = b3[tid];

  if (tid < EE) {
    const float ccx = outC[cs * 3 + 0], ccy = outC[cs * 3 + 1], ccz = outC[cs * 3 + 2];
    int row;
    bool valid;
    if (tid < KK) {
      const int cn = cnt[cs];
      valid = tid < cn;
      const int j = valid ? nbr[cs * KK + tid] : 0;
      row = b * NN + j;
    } else {
      // PyG add_self_loops quirk: src is flat point index dflat = b*S+s = cs
      valid = true;
      row = cs;
    }
    for (int f = 0; f < FIN; ++f) sF[tid][f] = x[(size_t)row * FIN + f];
    sF[tid][16] = pos[(size_t)row * 3 + 0] - ccx;
    sF[tid][17] = pos[(size_t)row * 3 + 1] - ccy;
    sF[tid][18] = pos[(size_t)row * 3 + 2] - ccz;
    sValid[tid] = valid ? 1 : 0;
  }
  __syncthreads();
  for (int e = half; e < EE; e += 2) {
    float acc = b1c;
#pragma unroll
    for (int k = 0; k < 19; ++k) acc += sF[e][k] * w1c[k];
    sH1[e][c] = fmaxf(acc, 0.0f);
  }
  __syncthreads();
  for (int e = half; e < EE; e += 2) {
    float acc = b2c;
#pragma unroll
    for (int k = 0; k < 64; ++k) acc += sH1[e][k] * w2c[k];
    sH2[e][c] = fmaxf(acc, 0.0f);
  }
  __syncthreads();
  float mx = -1e30f;
  for (int e = 0; e < EE; ++e) {
    if (sValid[e]) {
      float acc = b3c;
#pragma unroll
      for (int k = 0; k < 64; ++k) acc += sH2[e][k] * w3c[k];
      mx = fmaxf(mx, acc);
    }
  }
  outX[(size_t)cs * 128 + tid] = mx;
}

extern "C" void kernel_launch(void* const* d_in, const int* in_sizes, int n_in,
                              void* d_out, int out_size, void* d_ws, size_t ws_size,
                              hipStream_t stream) {
  const float* x = (const float*)d_in[0];
  const float* pos = (const float*)d_in[1];
  const float* W1 = (const float*)d_in[3];
  const float* b1 = (const float*)d_in[4];
  const float* W2 = (const float*)d_in[5];
  const float* b2 = (const float*)d_in[6];
  const float* W3 = (const float*)d_in[7];
  const float* b3 = (const float*)d_in[8];

  float* out = (float*)d_out;
  float* outX = out;                               // [B*S,128]
  float* outC = out + (size_t)BB * SS * 128;       // [B*S,3]
  float* outB = outC + (size_t)BB * SS * 3;        // [B*S]

  float4* cellpts = (float4*)d_ws;                         // BB*NN float4
  float4* bboxLo = cellpts + (size_t)BB * NN;              // BB*256
  float4* bboxHi = bboxLo + BB * NCHUNK;                   // BB*256
  int* idx = (int*)(bboxHi + BB * NCHUNK);                 // BB*SS
  int* nbr = idx + BB * SS;                                // BB*SS*KK
  int* cnt = nbr + (size_t)BB * SS * KK;                   // BB*SS

  hipLaunchKernelGGL(bin_kernel, dim3(BB), dim3(512), 0, stream, pos, cellpts, bboxLo, bboxHi);
  hipLaunchKernelGGL(fps_kernel, dim3(BB), dim3(FPS_T), 0, stream, pos, cellpts, bboxLo, bboxHi, idx);
  hipLaunchKernelGGL(ballq_kernel, dim3(BB * SS / 4), dim3(256), 0, stream,
                     pos, idx, nbr, cnt, outC, outB);
  hipLaunchKernelGGL(mlp_kernel, dim3(BB * SS), dim3(128), 0, stream,
                     x, pos, nbr, cnt, W1, b1, W2, b2, W3, b3, outC, outX);
}